// Round 1
// 520.933 us; speedup vs baseline: 1.0081x; 1.0081x over previous
//
#include <hip/hip_runtime.h>

#define H_N   100000
#define E_N   200000
#define NI_N  1000000
#define LN_EPS 1e-5f

#define NBUCK  1563        // ceil(200000/128) == ceil(100000/64)
#define SEGB_E 128
#define SEGB_H 64
#define CAP    1024        // total per-bucket capacity (mean 640, sigma ~25)
#define SUBCAP 192         // per-XCD sub-bucket capacity (mean 80, sigma ~9)

typedef __attribute__((ext_vector_type(8))) short bf16x8;
typedef __attribute__((ext_vector_type(4))) float floatx4;

__device__ inline unsigned short f2bf(float f) {
  unsigned u = __builtin_bit_cast(unsigned, f);
  u += 0x7fffu + ((u >> 16) & 1u);           // round-to-nearest-even
  return (unsigned short)(u >> 16);
}
__device__ inline float bf2f(unsigned short s) {
  unsigned u = ((unsigned)s) << 16;
  return __builtin_bit_cast(float, u);
}
__device__ inline unsigned get_xcc() {
  unsigned x;
  asm volatile("s_getreg_b32 %0, hwreg(HW_REG_XCC_ID)" : "=s"(x));
  return x & 7;
}

// ---------------------------------------------------------------------------
// fp32 -> bf16 conversion, 4 elements/thread
// ---------------------------------------------------------------------------
__global__ __launch_bounds__(256) void k_cvt_bf16(const float4* __restrict__ src,
                                                  unsigned short* __restrict__ dst,
                                                  int n4) {
  int i = blockIdx.x * 256 + threadIdx.x;
  if (i >= n4) return;
  float4 v = src[i];
  union { unsigned short us[4]; unsigned long long u64; } p;
  p.us[0] = f2bf(v.x); p.us[1] = f2bf(v.y);
  p.us[2] = f2bf(v.z); p.us[3] = f2bf(v.w);
  *(unsigned long long*)(dst + (size_t)i * 4) = p.u64;
}

// ---------------------------------------------------------------------------
// Bucket binning, XCD-local: each bucket has 8 per-XCD sub-regions so all
// writes to a sub-region stay within one XCD's L2 (lines fill -> ~1x
// writeback). Layout: pairs[((xcc*NBUCK)+bucket)*SUBCAP + slot].
// ---------------------------------------------------------------------------
__global__ __launch_bounds__(256) void k_bucket(
    const int* __restrict__ fg, const int* __restrict__ res,
    int* __restrict__ bcnt_e, int* __restrict__ bcnt_h,
    unsigned* __restrict__ pairs_e, unsigned* __restrict__ pairs_h) {
  int i = blockIdx.x * 256 + threadIdx.x;
  if (i >= NI_N) return;
  unsigned xcc = get_xcc();
  int f = fg[i], r = res[i];
  int be = r >> 7, se = r & 127;
  int pe = atomicAdd(bcnt_e + xcc * NBUCK + be, 1);
  if (pe < SUBCAP)
    pairs_e[((size_t)xcc * NBUCK + be) * SUBCAP + pe] =
        ((unsigned)se << 24) | (unsigned)f;
  int bh = f >> 6, sh = f & 63;
  int ph = atomicAdd(bcnt_h + xcc * NBUCK + bh, 1);
  if (ph < SUBCAP)
    pairs_h[((size_t)xcc * NBUCK + bh) * SUBCAP + ph] =
        ((unsigned)sh << 24) | (unsigned)r;
}

// ---------------------------------------------------------------------------
// Per-bucket: concat 8 sub-lists -> LDS counting sort -> gather-mean.
// ---------------------------------------------------------------------------
__global__ __launch_bounds__(256) void k_seg_mean(
    const unsigned short* __restrict__ rows, const unsigned* __restrict__ pairs,
    const int* __restrict__ bcnt, unsigned short* __restrict__ outm,
    int nseg, int segb) {
  __shared__ unsigned raw[CAP];
  __shared__ unsigned sortedp[CAP];
  __shared__ int cnts[129];
  __shared__ int curs[128];
  const int b = blockIdx.x;
  const int t = threadIdx.x;

  int total = 0;
#pragma unroll
  for (int x = 0; x < 8; ++x) {
    int c = min(bcnt[x * NBUCK + b], SUBCAP);
    const unsigned* src = pairs + ((size_t)x * NBUCK + b) * SUBCAP;
    for (int j = t; j < c; j += 256) {
      int d = total + j;
      if (d < CAP) raw[d] = src[j];
    }
    total += c;
  }
  const int cnt = min(total, CAP);
  if (t <= segb) cnts[t] = 0;
  __syncthreads();
  for (int j = t; j < cnt; j += 256)
    atomicAdd(&cnts[(raw[j] >> 24) + 1], 1);
  __syncthreads();
  for (int d = 1; d <= segb; d <<= 1) {
    int v = 0;
    if (t <= segb && t >= d) v = cnts[t - d];
    __syncthreads();
    if (t <= segb) cnts[t] += v;
    __syncthreads();
  }
  if (t < segb) curs[t] = cnts[t];
  __syncthreads();
  for (int j = t; j < cnt; j += 256) {
    unsigned p = raw[j];
    int s = p >> 24;
    int d = atomicAdd(&curs[s], 1);
    sortedp[d] = p & 0xFFFFFFu;
  }
  __syncthreads();

  const int wave = t >> 6, lane = t & 63;
  const int segs_here = min(segb, nseg - b * segb);
  for (int s = wave; s < segs_here; s += 4) {
    int o = cnts[s], e = cnts[s + 1];
    float a0 = 0.f, a1 = 0.f;
    int j = o;
    for (; j + 1 < e; j += 2) {
      int i0 = sortedp[j], i1 = sortedp[j + 1];
      unsigned v0 = *(const unsigned*)(rows + (size_t)i0 * 128 + lane * 2);
      unsigned v1 = *(const unsigned*)(rows + (size_t)i1 * 128 + lane * 2);
      a0 += bf2f((unsigned short)(v0 & 0xffffu)) + bf2f((unsigned short)(v1 & 0xffffu));
      a1 += bf2f((unsigned short)(v0 >> 16)) + bf2f((unsigned short)(v1 >> 16));
    }
    if (j < e) {
      int i0 = sortedp[j];
      unsigned v0 = *(const unsigned*)(rows + (size_t)i0 * 128 + lane * 2);
      a0 += bf2f((unsigned short)(v0 & 0xffffu));
      a1 += bf2f((unsigned short)(v0 >> 16));
    }
    float inv = (e > o) ? 1.0f / (float)(e - o) : 0.0f;
    unsigned ov = (unsigned)f2bf(a0 * inv) | ((unsigned)f2bf(a1 * inv) << 16);
    *(unsigned*)(outm + (size_t)(b * segb + s) * 128 + lane * 2) = ov;
  }
}

// ---------------------------------------------------------------------------
// Edge MLP, N-split: block = 64 edges, each wave owns 32 output cols.
// __launch_bounds__(256, 4): cap VGPR at 128 so B1/B2 weight fragments stay
// register-resident (at 64 VGPR the compiler rematerialized every weight load
// inside the MFMA loop -> latency-bound, MfmaUtil 6.5%).
// attr is pre-converted to bf16 (attr_bf) so the inner loop has no f2bf.
// ---------------------------------------------------------------------------
__global__ __launch_bounds__(256, 4) void k_edge_mlp(
    const short* __restrict__ edge_mean, const short* __restrict__ attr_bf,
    const short* __restrict__ w1, const float* __restrict__ b1,
    const short* __restrict__ w2, const float* __restrict__ b2,
    unsigned short* __restrict__ edge_msg) {
  __shared__ short h1s[64][136];
  const int wave = threadIdx.x >> 6;
  const int lane = threadIdx.x & 63;
  const int row  = lane & 15;
  const int quad = lane >> 4;
  const int e0   = blockIdx.x * 64;
  const int cb   = wave * 32;

  bf16x8 B1[2][6];
#pragma unroll
  for (int nl = 0; nl < 2; ++nl)
#pragma unroll
    for (int ks = 0; ks < 6; ++ks)
      B1[nl][ks] = *(const bf16x8*)(w1 + (size_t)(cb + nl * 16 + row) * 192 +
                                    ks * 32 + quad * 8);

  floatx4 acc[4][2];
#pragma unroll
  for (int m = 0; m < 4; ++m)
#pragma unroll
    for (int nl = 0; nl < 2; ++nl) acc[m][nl] = (floatx4){0.f, 0.f, 0.f, 0.f};

#pragma unroll
  for (int ks = 0; ks < 6; ++ks) {
    bf16x8 a[4];
#pragma unroll
    for (int m = 0; m < 4; ++m) {
      int e = e0 + m * 16 + row;
      if (ks < 4) {
        a[m] = *(const bf16x8*)(edge_mean + (size_t)e * 128 + ks * 32 + quad * 8);
      } else {
        a[m] = *(const bf16x8*)(attr_bf + (size_t)e * 64 + (ks - 4) * 32 + quad * 8);
      }
    }
#pragma unroll
    for (int m = 0; m < 4; ++m)
#pragma unroll
      for (int nl = 0; nl < 2; ++nl)
        acc[m][nl] = __builtin_amdgcn_mfma_f32_16x16x32_bf16(a[m], B1[nl][ks],
                                                             acc[m][nl], 0, 0, 0);
  }

#pragma unroll
  for (int nl = 0; nl < 2; ++nl) {
    float bias = b1[cb + nl * 16 + row];
#pragma unroll
    for (int m = 0; m < 4; ++m)
#pragma unroll
      for (int r = 0; r < 4; ++r)
        h1s[m * 16 + quad * 4 + r][cb + nl * 16 + row] =
            (short)f2bf(fmaxf(acc[m][nl][r] + bias, 0.0f));
  }

  bf16x8 B2[2][4];
#pragma unroll
  for (int nl = 0; nl < 2; ++nl)
#pragma unroll
    for (int ks = 0; ks < 4; ++ks)
      B2[nl][ks] = *(const bf16x8*)(w2 + (size_t)(cb + nl * 16 + row) * 128 +
                                    ks * 32 + quad * 8);
  __syncthreads();

  floatx4 acc2[4][2];
#pragma unroll
  for (int m = 0; m < 4; ++m)
#pragma unroll
    for (int nl = 0; nl < 2; ++nl) acc2[m][nl] = (floatx4){0.f, 0.f, 0.f, 0.f};

#pragma unroll
  for (int ks = 0; ks < 4; ++ks) {
    bf16x8 a[4];
#pragma unroll
    for (int m = 0; m < 4; ++m)
      a[m] = *(const bf16x8*)&h1s[m * 16 + row][ks * 32 + quad * 8];
#pragma unroll
    for (int m = 0; m < 4; ++m)
#pragma unroll
      for (int nl = 0; nl < 2; ++nl)
        acc2[m][nl] = __builtin_amdgcn_mfma_f32_16x16x32_bf16(a[m], B2[nl][ks],
                                                              acc2[m][nl], 0, 0, 0);
  }

#pragma unroll
  for (int nl = 0; nl < 2; ++nl) {
    int col = cb + nl * 16 + row;
    float bias = b2[col];
#pragma unroll
    for (int m = 0; m < 4; ++m)
#pragma unroll
      for (int r = 0; r < 4; ++r)
        edge_msg[(size_t)(e0 + m * 16 + quad * 4 + r) * 128 + col] =
            f2bf(acc2[m][nl][r] + bias);
  }
}

// ---------------------------------------------------------------------------
// Node MLP + residual projection + relu + LayerNorm, N-split.
// __launch_bounds__(256, 3): cap VGPR ~170 so B2/Bp/acc2/at/ax (~145 VGPR)
// stay register-resident.
// ---------------------------------------------------------------------------
__global__ __launch_bounds__(256, 3) void k_node_mlp_ln(
    const short* __restrict__ node_msg, const short* __restrict__ xh_bf,
    const short* __restrict__ wp, const float* __restrict__ bp,
    const short* __restrict__ wn1, const float* __restrict__ bn1,
    const short* __restrict__ wn2, const float* __restrict__ bn2,
    const float* __restrict__ gamma, const float* __restrict__ beta,
    float* __restrict__ out) {
  __shared__ short h1s[64][136];
  __shared__ float2 part[64][4];
  const int wave = threadIdx.x >> 6;
  const int lane = threadIdx.x & 63;
  const int row  = lane & 15;
  const int quad = lane >> 4;
  const int n0   = blockIdx.x * 64;
  const int cb   = wave * 32;

  bf16x8 B1[2][4];
#pragma unroll
  for (int nl = 0; nl < 2; ++nl)
#pragma unroll
    for (int ks = 0; ks < 4; ++ks)
      B1[nl][ks] = *(const bf16x8*)(wn1 + (size_t)(cb + nl * 16 + row) * 128 +
                                    ks * 32 + quad * 8);

  floatx4 acc[4][2];
#pragma unroll
  for (int m = 0; m < 4; ++m)
#pragma unroll
    for (int nl = 0; nl < 2; ++nl) acc[m][nl] = (floatx4){0.f, 0.f, 0.f, 0.f};

#pragma unroll
  for (int ks = 0; ks < 4; ++ks) {
    bf16x8 a[4];
#pragma unroll
    for (int m = 0; m < 4; ++m) {
      int n = n0 + m * 16 + row;
      a[m] = *(const bf16x8*)(node_msg + (size_t)n * 128 + ks * 32 + quad * 8);
    }
#pragma unroll
    for (int m = 0; m < 4; ++m)
#pragma unroll
      for (int nl = 0; nl < 2; ++nl)
        acc[m][nl] = __builtin_amdgcn_mfma_f32_16x16x32_bf16(a[m], B1[nl][ks],
                                                             acc[m][nl], 0, 0, 0);
  }

#pragma unroll
  for (int nl = 0; nl < 2; ++nl) {
    float bias = bn1[cb + nl * 16 + row];
#pragma unroll
    for (int m = 0; m < 4; ++m)
#pragma unroll
      for (int r = 0; r < 4; ++r)
        h1s[m * 16 + quad * 4 + r][cb + nl * 16 + row] =
            (short)f2bf(fmaxf(acc[m][nl][r] + bias, 0.0f));
  }

  bf16x8 B2[2][4], Bp[2][4];
#pragma unroll
  for (int nl = 0; nl < 2; ++nl)
#pragma unroll
    for (int ks = 0; ks < 4; ++ks) {
      B2[nl][ks] = *(const bf16x8*)(wn2 + (size_t)(cb + nl * 16 + row) * 128 +
                                    ks * 32 + quad * 8);
      Bp[nl][ks] = *(const bf16x8*)(wp + (size_t)(cb + nl * 16 + row) * 128 +
                                    ks * 32 + quad * 8);
    }
  __syncthreads();

  floatx4 acc2[4][2];
#pragma unroll
  for (int m = 0; m < 4; ++m)
#pragma unroll
    for (int nl = 0; nl < 2; ++nl) acc2[m][nl] = (floatx4){0.f, 0.f, 0.f, 0.f};

#pragma unroll
  for (int ks = 0; ks < 4; ++ks) {
    bf16x8 at[4], ax[4];
#pragma unroll
    for (int m = 0; m < 4; ++m) {
      at[m] = *(const bf16x8*)&h1s[m * 16 + row][ks * 32 + quad * 8];
      int n = n0 + m * 16 + row;
      ax[m] = *(const bf16x8*)(xh_bf + (size_t)n * 128 + ks * 32 + quad * 8);
    }
#pragma unroll
    for (int m = 0; m < 4; ++m)
#pragma unroll
      for (int nl = 0; nl < 2; ++nl) {
        acc2[m][nl] = __builtin_amdgcn_mfma_f32_16x16x32_bf16(at[m], B2[nl][ks],
                                                              acc2[m][nl], 0, 0, 0);
        acc2[m][nl] = __builtin_amdgcn_mfma_f32_16x16x32_bf16(ax[m], Bp[nl][ks],
                                                              acc2[m][nl], 0, 0, 0);
      }
  }

  float z[4][2][4];
#pragma unroll
  for (int m = 0; m < 4; ++m) {
    float s[4], ss[4];
#pragma unroll
    for (int r = 0; r < 4; ++r) { s[r] = 0.f; ss[r] = 0.f; }
#pragma unroll
    for (int nl = 0; nl < 2; ++nl) {
      float bias = bp[cb + nl * 16 + row] + bn2[cb + nl * 16 + row];
#pragma unroll
      for (int r = 0; r < 4; ++r) {
        float v = fmaxf(acc2[m][nl][r] + bias, 0.0f);
        z[m][nl][r] = v;
        s[r] += v;
        ss[r] += v * v;
      }
    }
#pragma unroll
    for (int r = 0; r < 4; ++r) {
#pragma unroll
      for (int msk = 1; msk < 16; msk <<= 1) {
        s[r]  += __shfl_xor(s[r],  msk, 64);
        ss[r] += __shfl_xor(ss[r], msk, 64);
      }
      if (row == 0) part[m * 16 + quad * 4 + r][wave] = make_float2(s[r], ss[r]);
    }
  }
  __syncthreads();

#pragma unroll
  for (int m = 0; m < 4; ++m)
#pragma unroll
    for (int r = 0; r < 4; ++r) {
      int rr = m * 16 + quad * 4 + r;
      float2 p0 = part[rr][0], p1 = part[rr][1], p2 = part[rr][2], p3 = part[rr][3];
      float mean = (p0.x + p1.x + p2.x + p3.x) * (1.0f / 128.0f);
      float var  = (p0.y + p1.y + p2.y + p3.y) * (1.0f / 128.0f) - mean * mean;
      float rstd = rsqrtf(var + LN_EPS);
      int n = n0 + rr;
      if (n < H_N) {
#pragma unroll
        for (int nl = 0; nl < 2; ++nl) {
          int col = cb + nl * 16 + row;
          out[(size_t)n * 128 + col] =
              (z[m][nl][r] - mean) * rstd * gamma[col] + beta[col];
        }
      }
    }
}

// ---------------------------------------------------------------------------
extern "C" void kernel_launch(void* const* d_in, const int* in_sizes, int n_in,
                              void* d_out, int out_size, void* d_ws, size_t ws_size,
                              hipStream_t stream) {
  const float* x_h   = (const float*)d_in[0];
  const float* attr  = (const float*)d_in[1];
  const float* Wp    = (const float*)d_in[2];
  const float* bp    = (const float*)d_in[3];
  const float* We1   = (const float*)d_in[4];
  const float* be1   = (const float*)d_in[5];
  const float* We2   = (const float*)d_in[6];
  const float* be2   = (const float*)d_in[7];
  const float* Wn1   = (const float*)d_in[8];
  const float* bn1   = (const float*)d_in[9];
  const float* Wn2   = (const float*)d_in[10];
  const float* bn2   = (const float*)d_in[11];
  const float* gamma = (const float*)d_in[12];
  const float* beta  = (const float*)d_in[13];
  const int*   fg    = (const int*)d_in[14];
  const int*   res   = (const int*)d_in[15];
  float* out = (float*)d_out;

  // ---- workspace layout ----
  int* bcnt_e = (int*)d_ws;                         // 8*NBUCK
  int* bcnt_h = bcnt_e + 8 * NBUCK;                 // 8*NBUCK
  unsigned* pairs_e = (unsigned*)(bcnt_h + 8 * NBUCK);  // 8*NBUCK*SUBCAP
  unsigned* pairs_h = pairs_e + (size_t)8 * NBUCK * SUBCAP;
  unsigned short* xh_bf     = (unsigned short*)(pairs_h + (size_t)8 * NBUCK * SUBCAP);
  unsigned short* edge_mean = xh_bf + (size_t)H_N * 128;
  unsigned short* edge_msg  = edge_mean + (size_t)E_N * 128;
  unsigned short* node_msg  = edge_msg + (size_t)E_N * 128;
  short* w1  = (short*)(node_msg + (size_t)H_N * 128);
  short* w2  = w1 + 128 * 192;
  short* wn1 = w2 + 128 * 128;
  short* wn2 = wn1 + 128 * 128;
  short* wp  = wn2 + 128 * 128;
  short* attr_bf = wp + 128 * 128;                  // E_N*64 bf16

  hipMemsetAsync(bcnt_e, 0, (size_t)16 * NBUCK * 4, stream);

  {
    int n4 = H_N * 128 / 4;
    k_cvt_bf16<<<(n4 + 255) / 256, 256, 0, stream>>>((const float4*)x_h, xh_bf, n4);
    n4 = E_N * 64 / 4;
    k_cvt_bf16<<<(n4 + 255) / 256, 256, 0, stream>>>((const float4*)attr, (unsigned short*)attr_bf, n4);
    n4 = 128 * 192 / 4;
    k_cvt_bf16<<<(n4 + 255) / 256, 256, 0, stream>>>((const float4*)We1, (unsigned short*)w1, n4);
    n4 = 128 * 128 / 4;
    k_cvt_bf16<<<(n4 + 255) / 256, 256, 0, stream>>>((const float4*)We2, (unsigned short*)w2, n4);
    k_cvt_bf16<<<(n4 + 255) / 256, 256, 0, stream>>>((const float4*)Wn1, (unsigned short*)wn1, n4);
    k_cvt_bf16<<<(n4 + 255) / 256, 256, 0, stream>>>((const float4*)Wn2, (unsigned short*)wn2, n4);
    k_cvt_bf16<<<(n4 + 255) / 256, 256, 0, stream>>>((const float4*)Wp, (unsigned short*)wp, n4);
  }

  k_bucket<<<(NI_N + 255) / 256, 256, 0, stream>>>(fg, res, bcnt_e, bcnt_h,
                                                   pairs_e, pairs_h);

  k_seg_mean<<<NBUCK, 256, 0, stream>>>(xh_bf, pairs_e, bcnt_e,
                                        edge_mean, E_N, SEGB_E);
  k_edge_mlp<<<E_N / 64, 256, 0, stream>>>((const short*)edge_mean, attr_bf,
                                           w1, be1, w2, be2, edge_msg);
  k_seg_mean<<<NBUCK, 256, 0, stream>>>(edge_msg, pairs_h, bcnt_h,
                                        node_msg, H_N, SEGB_H);
  k_node_mlp_ln<<<(H_N + 63) / 64, 256, 0, stream>>>((const short*)node_msg,
                                                     (const short*)xh_bf,
                                                     wp, bp, wn1, bn1, wn2, bn2,
                                                     gamma, beta, out);
}